// Round 1
// baseline (2030.920 us; speedup 1.0000x reference)
//
#include <hip/hip_runtime.h>
#include <cmath>

#define B_  4
#define S_  2048
#define D_  1024
#define H_  16
#define DH_ 64   // DQ = DV

// ------------------------------------------------------------------ QKV GEMM
// C[8192 x 64] per (mat, head): A = x [8192,1024], W = [1024,64] row-major.
// Block: 256 threads = 16x16, tile 128x64, BK=32, each thread 8x4 outputs.
__global__ __launch_bounds__(256)
void qkv_kernel(const float* __restrict__ x,
                const float* __restrict__ Wq,
                const float* __restrict__ Wk,
                const float* __restrict__ Wv,
                float* __restrict__ Qo,
                float* __restrict__ Ko,
                float* __restrict__ Vo)
{
    __shared__ float As[32][132];   // k-major; pitch 132: 16B-aligned rows, <=4-way store conflicts
    __shared__ float Bs[32][64];

    const int tid = threadIdx.x;
    const int ty  = tid >> 4;
    const int tx  = tid & 15;
    const int row0 = blockIdx.x * 128;
    const int y    = blockIdx.y;        // 0..47
    const int mat  = y >> 4;            // 0:Q 1:K 2:V
    const int h    = y & 15;

    const float* W = (mat == 0 ? Wq : (mat == 1 ? Wk : Wv)) + (size_t)h * D_ * DH_;
    float* Out     = (mat == 0 ? Qo : (mat == 1 ? Ko : Vo)) + (size_t)h * S_ * DH_;

    float acc[8][4];
    #pragma unroll
    for (int i = 0; i < 8; ++i)
        #pragma unroll
        for (int j = 0; j < 4; ++j) acc[i][j] = 0.f;

    for (int kb = 0; kb < D_; kb += 32) {
        // A tile 128x32 -> As[k][row] (transposed, k-major)
        #pragma unroll
        for (int t = 0; t < 4; ++t) {
            int f   = tid + t * 256;    // 0..1023 float4 ids
            int row = f >> 3;           // 0..127
            int k4  = f & 7;            // 0..7
            float4 v = *(const float4*)(x + (size_t)(row0 + row) * D_ + kb + k4 * 4);
            As[k4 * 4 + 0][row] = v.x;
            As[k4 * 4 + 1][row] = v.y;
            As[k4 * 4 + 2][row] = v.z;
            As[k4 * 4 + 3][row] = v.w;
        }
        // B tile 32x64 row-major
        #pragma unroll
        for (int t = 0; t < 2; ++t) {
            int f  = tid + t * 256;     // 0..511
            int k  = f >> 4;
            int e4 = f & 15;
            *(float4*)&Bs[k][e4 * 4] = *(const float4*)(W + (size_t)(kb + k) * DH_ + e4 * 4);
        }
        __syncthreads();
        #pragma unroll
        for (int kk = 0; kk < 32; ++kk) {
            float4 a0 = *(const float4*)&As[kk][ty * 8];
            float4 a1 = *(const float4*)&As[kk][ty * 8 + 4];
            float4 b0 = *(const float4*)&Bs[kk][tx * 4];
            float av[8] = {a0.x, a0.y, a0.z, a0.w, a1.x, a1.y, a1.z, a1.w};
            float bv[4] = {b0.x, b0.y, b0.z, b0.w};
            #pragma unroll
            for (int i = 0; i < 8; ++i)
                #pragma unroll
                for (int j = 0; j < 4; ++j)
                    acc[i][j] = fmaf(av[i], bv[j], acc[i][j]);
        }
        __syncthreads();
    }
    // write to [B][H][S][DH] (Out already offset by h)
    #pragma unroll
    for (int i = 0; i < 8; ++i) {
        int r = row0 + ty * 8 + i;
        int b = r >> 11;                // /2048
        int s = r & (S_ - 1);
        float4 v = make_float4(acc[i][0], acc[i][1], acc[i][2], acc[i][3]);
        *(float4*)(Out + (size_t)b * H_ * S_ * DH_ + (size_t)s * DH_ + tx * 4) = v;
    }
}

// ------------------------------------------------------------- flash attention
// One block = 64 Q rows of one (b,h). Iterate 32 K/V tiles of 64 rows.
// Threads 16x16, each owns a 4x4 score/output subtile. Softmax reductions via
// __shfl_xor across the 16 lanes sharing a row group (same ty).
__global__ __launch_bounds__(256)
void attn_kernel(const float* __restrict__ Q,
                 const float* __restrict__ K,
                 const float* __restrict__ V,
                 float* __restrict__ Oc)   // concat [B][S][H*DH]
{
    __shared__ float Qts[DH_][64];  // transposed Q tile: [k][row]
    __shared__ float Ks[64][65];    // K tile [keyrow][feat]; aliased as P[qrow][keyrow] later
    __shared__ float Vs[64][64];    // V tile [keyrow][feat]

    const int tid = threadIdx.x;
    const int ty  = tid >> 4;
    const int tx  = tid & 15;
    const int qt  = blockIdx.x;     // 0..31
    const int bh  = blockIdx.y;     // 0..63
    const int b   = bh >> 4;
    const int h   = bh & 15;
    const float* Qbh = Q + (size_t)bh * S_ * DH_;
    const float* Kbh = K + (size_t)bh * S_ * DH_;
    const float* Vbh = V + (size_t)bh * S_ * DH_;

    // stage Q transposed (once; write conflicts amortized over 32 tiles)
    #pragma unroll
    for (int t = 0; t < 4; ++t) {
        int f   = tid + t * 256;
        int row = f >> 4;           // 0..63
        int c4  = f & 15;
        float4 v = *(const float4*)(Qbh + (size_t)(qt * 64 + row) * DH_ + c4 * 4);
        Qts[c4 * 4 + 0][row] = v.x;
        Qts[c4 * 4 + 1][row] = v.y;
        Qts[c4 * 4 + 2][row] = v.z;
        Qts[c4 * 4 + 3][row] = v.w;
    }

    float m_run[4], l_run[4], acc[4][4];
    #pragma unroll
    for (int i = 0; i < 4; ++i) {
        m_run[i] = -1e30f;
        l_run[i] = 0.f;
        #pragma unroll
        for (int j = 0; j < 4; ++j) acc[i][j] = 0.f;
    }
    const float scale = 0.125f;     // 1/sqrt(64)

    for (int kt = 0; kt < S_ / 64; ++kt) {
        __syncthreads();            // previous tile's P/V reads complete
        #pragma unroll
        for (int t = 0; t < 4; ++t) {
            int f   = tid + t * 256;
            int row = f >> 4;
            int c4  = f & 15;
            float4 kv = *(const float4*)(Kbh + (size_t)(kt * 64 + row) * DH_ + c4 * 4);
            Ks[row][c4 * 4 + 0] = kv.x;
            Ks[row][c4 * 4 + 1] = kv.y;
            Ks[row][c4 * 4 + 2] = kv.z;
            Ks[row][c4 * 4 + 3] = kv.w;
            float4 vv = *(const float4*)(Vbh + (size_t)(kt * 64 + row) * DH_ + c4 * 4);
            *(float4*)&Vs[row][c4 * 4] = vv;
        }
        __syncthreads();

        // S = Q * K^T (4x4 per thread)
        float s[4][4];
        #pragma unroll
        for (int i = 0; i < 4; ++i)
            #pragma unroll
            for (int j = 0; j < 4; ++j) s[i][j] = 0.f;
        #pragma unroll 16
        for (int kk = 0; kk < DH_; ++kk) {
            float4 a = *(const float4*)&Qts[kk][ty * 4];
            float av[4] = {a.x, a.y, a.z, a.w};
            float bv[4];
            #pragma unroll
            for (int j = 0; j < 4; ++j) bv[j] = Ks[tx * 4 + j][kk];
            #pragma unroll
            for (int i = 0; i < 4; ++i)
                #pragma unroll
                for (int j = 0; j < 4; ++j)
                    s[i][j] = fmaf(av[i], bv[j], s[i][j]);
        }

        // online softmax (per row; reduce over 16 lanes with same ty)
        float p[4][4];
        #pragma unroll
        for (int i = 0; i < 4; ++i) {
            #pragma unroll
            for (int j = 0; j < 4; ++j) s[i][j] *= scale;
            float mloc = fmaxf(fmaxf(s[i][0], s[i][1]), fmaxf(s[i][2], s[i][3]));
            #pragma unroll
            for (int off = 1; off < 16; off <<= 1)
                mloc = fmaxf(mloc, __shfl_xor(mloc, off));
            float mnew = fmaxf(m_run[i], mloc);
            float a    = __expf(m_run[i] - mnew);
            float rsum = 0.f;
            #pragma unroll
            for (int j = 0; j < 4; ++j) {
                p[i][j] = __expf(s[i][j] - mnew);
                rsum += p[i][j];
            }
            #pragma unroll
            for (int off = 1; off < 16; off <<= 1)
                rsum += __shfl_xor(rsum, off);
            l_run[i] = l_run[i] * a + rsum;
            m_run[i] = mnew;
            #pragma unroll
            for (int j = 0; j < 4; ++j) acc[i][j] *= a;
        }

        __syncthreads();            // all done reading Ks
        #pragma unroll
        for (int i = 0; i < 4; ++i)
            #pragma unroll
            for (int j = 0; j < 4; ++j)
                Ks[ty * 4 + i][tx * 4 + j] = p[i][j];   // P[qrow][keyrow]
        __syncthreads();

        // O += P * V
        #pragma unroll 8
        for (int t = 0; t < 64; ++t) {
            float4 vv = *(const float4*)&Vs[t][tx * 4];
            float vvv[4] = {vv.x, vv.y, vv.z, vv.w};
            #pragma unroll
            for (int i = 0; i < 4; ++i) {
                float pv = Ks[ty * 4 + i][t];
                #pragma unroll
                for (int j = 0; j < 4; ++j)
                    acc[i][j] = fmaf(pv, vvv[j], acc[i][j]);
            }
        }
    }

    // epilogue: normalize, write concat layout [B][S][H*DH]
    #pragma unroll
    for (int i = 0; i < 4; ++i) {
        int srow  = qt * 64 + ty * 4 + i;
        float inv = 1.f / l_run[i];
        float4 v = make_float4(acc[i][0] * inv, acc[i][1] * inv,
                               acc[i][2] * inv, acc[i][3] * inv);
        *(float4*)(Oc + (size_t)(b * S_ + srow) * (H_ * DH_) + h * DH_ + tx * 4) = v;
    }
}

// --------------------------------------------------------------- output proj
// out[8192,1024] = concat[8192,1024] @ Wo[1024,1024] + bo
__global__ __launch_bounds__(256)
void oproj_kernel(const float* __restrict__ A,
                  const float* __restrict__ Wo,
                  const float* __restrict__ bo,
                  float* __restrict__ out)
{
    __shared__ float As[32][132];
    __shared__ float Bs[32][64];

    const int tid = threadIdx.x;
    const int ty  = tid >> 4;
    const int tx  = tid & 15;
    const int row0 = blockIdx.x * 128;
    const int col0 = blockIdx.y * 64;

    float acc[8][4];
    #pragma unroll
    for (int i = 0; i < 8; ++i)
        #pragma unroll
        for (int j = 0; j < 4; ++j) acc[i][j] = 0.f;

    for (int kb = 0; kb < D_; kb += 32) {
        #pragma unroll
        for (int t = 0; t < 4; ++t) {
            int f   = tid + t * 256;
            int row = f >> 3;
            int k4  = f & 7;
            float4 v = *(const float4*)(A + (size_t)(row0 + row) * D_ + kb + k4 * 4);
            As[k4 * 4 + 0][row] = v.x;
            As[k4 * 4 + 1][row] = v.y;
            As[k4 * 4 + 2][row] = v.z;
            As[k4 * 4 + 3][row] = v.w;
        }
        #pragma unroll
        for (int t = 0; t < 2; ++t) {
            int f  = tid + t * 256;
            int k  = f >> 4;
            int e4 = f & 15;
            *(float4*)&Bs[k][e4 * 4] = *(const float4*)(Wo + (size_t)(kb + k) * D_ + col0 + e4 * 4);
        }
        __syncthreads();
        #pragma unroll
        for (int kk = 0; kk < 32; ++kk) {
            float4 a0 = *(const float4*)&As[kk][ty * 8];
            float4 a1 = *(const float4*)&As[kk][ty * 8 + 4];
            float4 b0 = *(const float4*)&Bs[kk][tx * 4];
            float av[8] = {a0.x, a0.y, a0.z, a0.w, a1.x, a1.y, a1.z, a1.w};
            float bv[4] = {b0.x, b0.y, b0.z, b0.w};
            #pragma unroll
            for (int i = 0; i < 8; ++i)
                #pragma unroll
                for (int j = 0; j < 4; ++j)
                    acc[i][j] = fmaf(av[i], bv[j], acc[i][j]);
        }
        __syncthreads();
    }
    float4 bias = *(const float4*)(bo + col0 + tx * 4);
    float bb[4] = {bias.x, bias.y, bias.z, bias.w};
    #pragma unroll
    for (int i = 0; i < 8; ++i) {
        int r = row0 + ty * 8 + i;
        float4 v = make_float4(acc[i][0] + bb[0], acc[i][1] + bb[1],
                               acc[i][2] + bb[2], acc[i][3] + bb[3]);
        *(float4*)(out + (size_t)r * D_ + col0 + tx * 4) = v;
    }
}

extern "C" void kernel_launch(void* const* d_in, const int* in_sizes, int n_in,
                              void* d_out, int out_size, void* d_ws, size_t ws_size,
                              hipStream_t stream) {
    const float* x  = (const float*)d_in[0];
    const float* Wq = (const float*)d_in[1];
    const float* Wk = (const float*)d_in[2];
    const float* Wv = (const float*)d_in[3];
    const float* Wo = (const float*)d_in[4];
    const float* bo = (const float*)d_in[5];
    float* out = (float*)d_out;

    const size_t per = (size_t)B_ * H_ * S_ * DH_;   // 8.39M floats
    float* Qb = (float*)d_ws;
    float* Kb = Qb + per;
    float* Vb = Kb + per;
    float* Cb = Vb + per;                            // concat [B][S][H*DH]

    dim3 g1(8192 / 128, 48);
    qkv_kernel<<<g1, 256, 0, stream>>>(x, Wq, Wk, Wv, Qb, Kb, Vb);

    dim3 g2(S_ / 64, B_ * H_);
    attn_kernel<<<g2, 256, 0, stream>>>(Qb, Kb, Vb, Cb);

    dim3 g3(8192 / 128, 1024 / 64);
    oproj_kernel<<<g3, 256, 0, stream>>>(Cb, Wo, bo, out);
}

// Round 2
// 1142.715 us; speedup vs baseline: 1.7773x; 1.7773x over previous
//
#include <hip/hip_runtime.h>
#include <cmath>

#define B_  4
#define S_  2048
#define D_  1024
#define H_  16
#define DH_ 64   // DQ = DV

typedef __attribute__((ext_vector_type(8))) short bf16x8;   // 8 bf16 = 4 VGPR (MFMA A/B frag)
typedef __attribute__((ext_vector_type(4))) float f32x4;    // MFMA C/D frag
typedef __attribute__((ext_vector_type(8))) unsigned short u16x8;

__device__ __forceinline__ unsigned short f2bf(float x) {
    unsigned int u = __builtin_bit_cast(unsigned int, x);
    u += 0x7fffu + ((u >> 16) & 1u);            // round-to-nearest-even
    return (unsigned short)(u >> 16);
}

// ------------------------------------------------------------------ QKV GEMM
// C[8192 x 64] per (mat, head), fp32 accumulate, bf16 output.
// Q is pre-scaled by 1/sqrt(DH) here so attention skips the score scaling.
__global__ __launch_bounds__(256)
void qkv_kernel(const float* __restrict__ x,
                const float* __restrict__ Wq,
                const float* __restrict__ Wk,
                const float* __restrict__ Wv,
                unsigned short* __restrict__ Qo,
                unsigned short* __restrict__ Ko,
                unsigned short* __restrict__ Vo)
{
    __shared__ float As[32][132];   // k-major
    __shared__ float Bs[32][64];

    const int tid = threadIdx.x;
    const int ty  = tid >> 4;
    const int tx  = tid & 15;
    const int row0 = blockIdx.x * 128;
    const int y    = blockIdx.y;        // 0..47
    const int mat  = y >> 4;            // 0:Q 1:K 2:V
    const int h    = y & 15;

    const float* W = (mat == 0 ? Wq : (mat == 1 ? Wk : Wv)) + (size_t)h * D_ * DH_;
    unsigned short* Out = (mat == 0 ? Qo : (mat == 1 ? Ko : Vo)) + (size_t)h * S_ * DH_;
    const float sc = (mat == 0) ? 0.125f : 1.0f;   // 1/sqrt(64) folded into Q

    float acc[8][4];
    #pragma unroll
    for (int i = 0; i < 8; ++i)
        #pragma unroll
        for (int j = 0; j < 4; ++j) acc[i][j] = 0.f;

    for (int kb = 0; kb < D_; kb += 32) {
        #pragma unroll
        for (int t = 0; t < 4; ++t) {
            int f   = tid + t * 256;
            int row = f >> 3;
            int k4  = f & 7;
            float4 v = *(const float4*)(x + (size_t)(row0 + row) * D_ + kb + k4 * 4);
            As[k4 * 4 + 0][row] = v.x;
            As[k4 * 4 + 1][row] = v.y;
            As[k4 * 4 + 2][row] = v.z;
            As[k4 * 4 + 3][row] = v.w;
        }
        #pragma unroll
        for (int t = 0; t < 2; ++t) {
            int f  = tid + t * 256;
            int k  = f >> 4;
            int e4 = f & 15;
            *(float4*)&Bs[k][e4 * 4] = *(const float4*)(W + (size_t)(kb + k) * DH_ + e4 * 4);
        }
        __syncthreads();
        #pragma unroll
        for (int kk = 0; kk < 32; ++kk) {
            float4 a0 = *(const float4*)&As[kk][ty * 8];
            float4 a1 = *(const float4*)&As[kk][ty * 8 + 4];
            float4 b0 = *(const float4*)&Bs[kk][tx * 4];
            float av[8] = {a0.x, a0.y, a0.z, a0.w, a1.x, a1.y, a1.z, a1.w};
            float bv[4] = {b0.x, b0.y, b0.z, b0.w};
            #pragma unroll
            for (int i = 0; i < 8; ++i)
                #pragma unroll
                for (int j = 0; j < 4; ++j)
                    acc[i][j] = fmaf(av[i], bv[j], acc[i][j]);
        }
        __syncthreads();
    }
    #pragma unroll
    for (int i = 0; i < 8; ++i) {
        int r = row0 + ty * 8 + i;
        int b = r >> 11;                // /2048
        int s = r & (S_ - 1);
        ushort4 w;
        w.x = f2bf(acc[i][0] * sc);
        w.y = f2bf(acc[i][1] * sc);
        w.z = f2bf(acc[i][2] * sc);
        w.w = f2bf(acc[i][3] * sc);
        *(ushort4*)(Out + (size_t)b * H_ * S_ * DH_ + (size_t)s * DH_ + tx * 4) = w;
    }
}

// ------------------------------------------------------- flash attention, MFMA
// Block = 256 threads = 4 waves; each wave owns 32 q-rows; block = 128 q-rows
// of one (b,h). KV tile = 64 keys. grid = (S/128, B*H).
// MFMA 16x16x32 bf16. Same assumed k-slot mapping used on both operands of
// each MFMA, so results are correct under any true per-lane k permutation.
__global__ __launch_bounds__(256, 2)
void attn_kernel(const unsigned short* __restrict__ Q,
                 const unsigned short* __restrict__ K,
                 const unsigned short* __restrict__ V,
                 float* __restrict__ Oc)   // concat [B][S][H*DV] fp32
{
    __shared__ unsigned short Vt[DH_][72];       // V tile transposed [d][key]
    __shared__ unsigned short Plds[4][32][72];   // per-wave P [qrow][key]

    const int tid  = threadIdx.x;
    const int wid  = tid >> 6;
    const int lane = tid & 63;
    const int lg   = lane >> 4;   // 0..3  (k-group / C-row group)
    const int lr   = lane & 15;   // 0..15 (A row / B col / C col)
    const int bh   = blockIdx.y;
    const int b    = bh >> 4;
    const int h    = bh & 15;
    const int q0   = blockIdx.x * 128 + wid * 32;

    const unsigned short* Qbh = Q + (size_t)bh * S_ * DH_;
    const unsigned short* Kbh = K + (size_t)bh * S_ * DH_;
    const unsigned short* Vbh = V + (size_t)bh * S_ * DH_;

    // Q fragments live in registers for the whole kernel: rb (row block), c (k chunk)
    bf16x8 qf[2][2];
    #pragma unroll
    for (int rb = 0; rb < 2; ++rb)
        #pragma unroll
        for (int c = 0; c < 2; ++c)
            qf[rb][c] = *(const bf16x8*)(Qbh + (size_t)(q0 + rb * 16 + lr) * DH_ + c * 32 + lg * 8);

    f32x4 oacc[2][4];
    float m_run[2][4], l_run[2][4];
    #pragma unroll
    for (int rb = 0; rb < 2; ++rb)
        #pragma unroll
        for (int r = 0; r < 4; ++r) {
            m_run[rb][r] = -1e30f;
            l_run[rb][r] = 0.f;
        }
    #pragma unroll
    for (int rb = 0; rb < 2; ++rb)
        #pragma unroll
        for (int nb = 0; nb < 4; ++nb)
            oacc[rb][nb] = (f32x4)(0.f);

    const int vkey = tid & 63;          // staging role: this thread's V row
    const int vd0  = (tid >> 6) * 16;   // and its 16 d-columns

    for (int kt = 0; kt < S_ / 64; ++kt) {
        // ---- stage V tile transposed (issue loads before barrier) ----
        u16x8 v0 = *(const u16x8*)(Vbh + (size_t)(kt * 64 + vkey) * DH_ + vd0);
        u16x8 v1 = *(const u16x8*)(Vbh + (size_t)(kt * 64 + vkey) * DH_ + vd0 + 8);
        __syncthreads();                // prior tile's Vt reads complete
        #pragma unroll
        for (int i = 0; i < 8; ++i) {
            Vt[vd0 + i][vkey]     = v0[i];
            Vt[vd0 + 8 + i][vkey] = v1[i];
        }
        __syncthreads();                // Vt visible

        // ---- S = Q K^T  (scores; Q pre-scaled) ----
        f32x4 sf[2][4];
        #pragma unroll
        for (int rb = 0; rb < 2; ++rb)
            #pragma unroll
            for (int nb = 0; nb < 4; ++nb)
                sf[rb][nb] = (f32x4)(0.f);
        #pragma unroll
        for (int c = 0; c < 2; ++c) {
            #pragma unroll
            for (int nb = 0; nb < 4; ++nb) {
                bf16x8 kf = *(const bf16x8*)(Kbh + (size_t)(kt * 64 + nb * 16 + lr) * DH_ + c * 32 + lg * 8);
                #pragma unroll
                for (int rb = 0; rb < 2; ++rb)
                    sf[rb][nb] = __builtin_amdgcn_mfma_f32_16x16x32_bf16(qf[rb][c], kf, sf[rb][nb], 0, 0, 0);
            }
        }

        // ---- online softmax (row = rb*16 + lg*4 + r, key col = nb*16 + lr) ----
        #pragma unroll
        for (int rb = 0; rb < 2; ++rb) {
            #pragma unroll
            for (int r = 0; r < 4; ++r) {
                float mloc = fmaxf(fmaxf(sf[rb][0][r], sf[rb][1][r]),
                                   fmaxf(sf[rb][2][r], sf[rb][3][r]));
                #pragma unroll
                for (int off = 1; off < 16; off <<= 1)
                    mloc = fmaxf(mloc, __shfl_xor(mloc, off));
                float mnew = fmaxf(m_run[rb][r], mloc);
                float a    = __expf(m_run[rb][r] - mnew);
                m_run[rb][r] = mnew;
                float rs = 0.f;
                #pragma unroll
                for (int nb = 0; nb < 4; ++nb) {
                    float p = __expf(sf[rb][nb][r] - mnew);
                    sf[rb][nb][r] = p;
                    rs += p;
                }
                #pragma unroll
                for (int off = 1; off < 16; off <<= 1)
                    rs += __shfl_xor(rs, off);
                l_run[rb][r] = l_run[rb][r] * a + rs;
                #pragma unroll
                for (int nb = 0; nb < 4; ++nb)
                    oacc[rb][nb][r] *= a;
            }
        }

        // ---- P -> bf16 -> per-wave LDS ----
        #pragma unroll
        for (int rb = 0; rb < 2; ++rb)
            #pragma unroll
            for (int nb = 0; nb < 4; ++nb)
                #pragma unroll
                for (int r = 0; r < 4; ++r)
                    Plds[wid][rb * 16 + lg * 4 + r][nb * 16 + lr] = f2bf(sf[rb][nb][r]);
        __syncthreads();                // P visible (uniform barrier; also orders Vt)

        // ---- O += P V ----
        #pragma unroll
        for (int c = 0; c < 2; ++c) {   // key chunks of 32
            bf16x8 pa[2];
            #pragma unroll
            for (int rb = 0; rb < 2; ++rb)
                pa[rb] = *(const bf16x8*)&Plds[wid][rb * 16 + lr][c * 32 + lg * 8];
            #pragma unroll
            for (int nb = 0; nb < 4; ++nb) {
                bf16x8 vf = *(const bf16x8*)&Vt[nb * 16 + lr][c * 32 + lg * 8];
                #pragma unroll
                for (int rb = 0; rb < 2; ++rb)
                    oacc[rb][nb] = __builtin_amdgcn_mfma_f32_16x16x32_bf16(pa[rb], vf, oacc[rb][nb], 0, 0, 0);
            }
        }
    }

    // ---- epilogue: normalize, write concat [B][S][H*DV] ----
    float* Obh = Oc + (size_t)b * S_ * (H_ * DH_) + h * DH_;
    #pragma unroll
    for (int rb = 0; rb < 2; ++rb) {
        #pragma unroll
        for (int r = 0; r < 4; ++r) {
            int row = q0 + rb * 16 + lg * 4 + r;
            float inv = 1.f / l_run[rb][r];
            #pragma unroll
            for (int nb = 0; nb < 4; ++nb)
                Obh[(size_t)row * (H_ * DH_) + nb * 16 + lr] = oacc[rb][nb][r] * inv;
        }
    }
}

// --------------------------------------------------------------- output proj
__global__ __launch_bounds__(256)
void oproj_kernel(const float* __restrict__ A,
                  const float* __restrict__ Wo,
                  const float* __restrict__ bo,
                  float* __restrict__ out)
{
    __shared__ float As[32][132];
    __shared__ float Bs[32][64];

    const int tid = threadIdx.x;
    const int ty  = tid >> 4;
    const int tx  = tid & 15;
    const int row0 = blockIdx.x * 128;
    const int col0 = blockIdx.y * 64;

    float acc[8][4];
    #pragma unroll
    for (int i = 0; i < 8; ++i)
        #pragma unroll
        for (int j = 0; j < 4; ++j) acc[i][j] = 0.f;

    for (int kb = 0; kb < D_; kb += 32) {
        #pragma unroll
        for (int t = 0; t < 4; ++t) {
            int f   = tid + t * 256;
            int row = f >> 3;
            int k4  = f & 7;
            float4 v = *(const float4*)(A + (size_t)(row0 + row) * D_ + kb + k4 * 4);
            As[k4 * 4 + 0][row] = v.x;
            As[k4 * 4 + 1][row] = v.y;
            As[k4 * 4 + 2][row] = v.z;
            As[k4 * 4 + 3][row] = v.w;
        }
        #pragma unroll
        for (int t = 0; t < 2; ++t) {
            int f  = tid + t * 256;
            int k  = f >> 4;
            int e4 = f & 15;
            *(float4*)&Bs[k][e4 * 4] = *(const float4*)(Wo + (size_t)(kb + k) * D_ + col0 + e4 * 4);
        }
        __syncthreads();
        #pragma unroll
        for (int kk = 0; kk < 32; ++kk) {
            float4 a0 = *(const float4*)&As[kk][ty * 8];
            float4 a1 = *(const float4*)&As[kk][ty * 8 + 4];
            float4 b0 = *(const float4*)&Bs[kk][tx * 4];
            float av[8] = {a0.x, a0.y, a0.z, a0.w, a1.x, a1.y, a1.z, a1.w};
            float bv[4] = {b0.x, b0.y, b0.z, b0.w};
            #pragma unroll
            for (int i = 0; i < 8; ++i)
                #pragma unroll
                for (int j = 0; j < 4; ++j)
                    acc[i][j] = fmaf(av[i], bv[j], acc[i][j]);
        }
        __syncthreads();
    }
    float4 bias = *(const float4*)(bo + col0 + tx * 4);
    float bb[4] = {bias.x, bias.y, bias.z, bias.w};
    #pragma unroll
    for (int i = 0; i < 8; ++i) {
        int r = row0 + ty * 8 + i;
        float4 v = make_float4(acc[i][0] + bb[0], acc[i][1] + bb[1],
                               acc[i][2] + bb[2], acc[i][3] + bb[3]);
        *(float4*)(out + (size_t)r * D_ + col0 + tx * 4) = v;
    }
}

extern "C" void kernel_launch(void* const* d_in, const int* in_sizes, int n_in,
                              void* d_out, int out_size, void* d_ws, size_t ws_size,
                              hipStream_t stream) {
    const float* x  = (const float*)d_in[0];
    const float* Wq = (const float*)d_in[1];
    const float* Wk = (const float*)d_in[2];
    const float* Wv = (const float*)d_in[3];
    const float* Wo = (const float*)d_in[4];
    const float* bo = (const float*)d_in[5];
    float* out = (float*)d_out;

    const size_t per = (size_t)B_ * H_ * S_ * DH_;     // 8.39M elements
    unsigned short* Qb = (unsigned short*)d_ws;
    unsigned short* Kb = Qb + per;
    unsigned short* Vb = Kb + per;
    float* Cb = (float*)((char*)d_ws + 3 * per * sizeof(unsigned short));

    dim3 g1(8192 / 128, 48);
    qkv_kernel<<<g1, 256, 0, stream>>>(x, Wq, Wk, Wv, Qb, Kb, Vb);

    dim3 g2(S_ / 128, B_ * H_);
    attn_kernel<<<g2, 256, 0, stream>>>(Qb, Kb, Vb, Cb);

    dim3 g3(8192 / 128, 1024 / 64);
    oproj_kernel<<<g3, 256, 0, stream>>>(Cb, Wo, bo, out);
}

// Round 3
// 412.585 us; speedup vs baseline: 4.9224x; 2.7696x over previous
//
#include <hip/hip_runtime.h>

#define B_  4
#define S_  2048
#define D_  1024
#define H_  16
#define DH_ 64

typedef __attribute__((ext_vector_type(8))) short bf16x8;
typedef __attribute__((ext_vector_type(4))) float f32x4;
typedef __attribute__((ext_vector_type(8))) unsigned short u16x8;

__device__ __forceinline__ unsigned short f2bf(float x) {
    unsigned int u = __builtin_bit_cast(unsigned int, x);
    u += 0x7fffu + ((u >> 16) & 1u);            // round-to-nearest-even
    return (unsigned short)(u >> 16);
}

// async global->LDS, 16B per lane (CK-style addrspace casts via integer)
__device__ __forceinline__ void cp16(const void* g, void* l) {
    typedef const __attribute__((address_space(1))) unsigned int* gp_t;
    typedef __attribute__((address_space(3))) unsigned int* lp_t;
    __builtin_amdgcn_global_load_lds((gp_t)(unsigned long long)(size_t)g,
                                     (lp_t)(unsigned int)(size_t)l, 16, 0, 0);
}

// ---------------------------------------------------------------- converts
// x[8192][1024] f32 -> bf16, 16B chunks XOR-swizzled within each 128B block
// (chunk' = chunk ^ (row&7)) so linear global_load_lds staging lands swizzled.
__global__ __launch_bounds__(256)
void conv_x(const float* __restrict__ x, unsigned short* __restrict__ xs)
{
    int gid = blockIdx.x * 256 + threadIdx.x;   // 1,048,576 chunks of 8 elems
    int row = gid >> 7;
    int rem = gid & 127;
    int blk = rem >> 3;
    int c   = rem & 7;
    const float* src = x + (size_t)row * 1024 + blk * 64 + c * 8;
    float4 a = *(const float4*)src;
    float4 b = *(const float4*)(src + 4);
    u16x8 v;
    v[0] = f2bf(a.x); v[1] = f2bf(a.y); v[2] = f2bf(a.z); v[3] = f2bf(a.w);
    v[4] = f2bf(b.x); v[5] = f2bf(b.y); v[6] = f2bf(b.z); v[7] = f2bf(b.w);
    *(u16x8*)(xs + (size_t)row * 1024 + blk * 64 + ((c ^ (row & 7)) * 8)) = v;
}

// Wq/Wk/Wv [16][1024][64] -> Wt[48][64][1024] bf16 (transposed, swizzled rows).
// Q's weights pre-scaled by 1/sqrt(DH).
__global__ __launch_bounds__(256)
void conv_wqkv(const float* __restrict__ Wq, const float* __restrict__ Wk,
               const float* __restrict__ Wv, unsigned short* __restrict__ Wt)
{
    __shared__ float Wl[64][65];
    const int tid = threadIdx.x;
    const int kt  = blockIdx.x;     // 16 k-tiles of 64
    const int y   = blockIdx.y;     // 48 (mat,head)
    const int mat = y >> 4, h = y & 15;
    const float* W = (mat == 0 ? Wq : (mat == 1 ? Wk : Wv)) + (size_t)h * 1024 * 64;
    const float sc = (mat == 0) ? 0.125f : 1.0f;
    #pragma unroll
    for (int i = 0; i < 4; ++i) {
        int idx = tid + i * 256;
        int kk = idx >> 4, c4 = (idx & 15) * 4;
        *(float4*)&Wl[kk][c4] = *(const float4*)&W[(size_t)(kt * 64 + kk) * 64 + c4];
    }
    __syncthreads();
    #pragma unroll
    for (int i = 0; i < 2; ++i) {
        int cid = tid + i * 256;
        int c = cid >> 3, kc = cid & 7;
        u16x8 v;
        #pragma unroll
        for (int j = 0; j < 8; ++j) v[j] = f2bf(Wl[kc * 8 + j][c] * sc);
        *(u16x8*)(Wt + ((size_t)y * 64 + c) * 1024 + kt * 64 + ((kc ^ (c & 7)) * 8)) = v;
    }
}

// Wo[1024][1024] -> Wot[1024][1024] bf16 (transposed, swizzled rows)
__global__ __launch_bounds__(256)
void conv_wo(const float* __restrict__ Wo, unsigned short* __restrict__ Wot)
{
    __shared__ float Wl[64][65];
    const int tid = threadIdx.x;
    const int kt = blockIdx.x, ct = blockIdx.y;
    #pragma unroll
    for (int i = 0; i < 4; ++i) {
        int idx = tid + i * 256;
        int kk = idx >> 4, c4 = (idx & 15) * 4;
        *(float4*)&Wl[kk][c4] = *(const float4*)&Wo[(size_t)(kt * 64 + kk) * 1024 + ct * 64 + c4];
    }
    __syncthreads();
    #pragma unroll
    for (int i = 0; i < 2; ++i) {
        int cid = tid + i * 256;
        int c = cid >> 3, kc = cid & 7;
        u16x8 v;
        #pragma unroll
        for (int j = 0; j < 8; ++j) v[j] = f2bf(Wl[kc * 8 + j][c]);
        *(u16x8*)(Wot + (size_t)(ct * 64 + c) * 1024 + kt * 64 + ((kc ^ (c & 7)) * 8)) = v;
    }
}

// ------------------------------------------------------------ QKV MFMA GEMM
// Per (mat,head) y: C[8192,64] = x[8192,1024] @ W_y[1024,64]. Tile 128x64,
// BK=64, 4 waves x (32 rows x 64 cols). 2-phase gload_lds double buffer.
__global__ __launch_bounds__(256, 2)
void qkv_mfma(const unsigned short* __restrict__ Xs,
              const unsigned short* __restrict__ Wt,
              unsigned short* __restrict__ Qo,
              unsigned short* __restrict__ Ko,
              unsigned short* __restrict__ Vo)
{
    __shared__ __align__(16) unsigned short As[2][128 * 64];
    __shared__ __align__(16) unsigned short Bs[2][64 * 64];

    const int tid  = threadIdx.x;
    const int wid  = tid >> 6;
    const int lane = tid & 63;
    const int lg   = lane >> 4;
    const int lr   = lane & 15;
    const int row0 = blockIdx.x * 128;
    const int y    = blockIdx.y;
    const int mat  = y >> 4;
    const int h    = y & 15;

    const unsigned short* Wh = Wt + (size_t)y * (64 * 1024);
    unsigned short* Out = (mat == 0 ? Qo : (mat == 1 ? Ko : Vo)) + (size_t)h * S_ * DH_;

    const int sr = tid >> 3;   // staging row base (+i*32)
    const int sc = tid & 7;    // staging 16B chunk

    f32x4 acc[2][4];
    #pragma unroll
    for (int rb = 0; rb < 2; ++rb)
        #pragma unroll
        for (int nb = 0; nb < 4; ++nb) acc[rb][nb] = (f32x4)(0.f);

    // prologue: stage k-tile 0
    #pragma unroll
    for (int i = 0; i < 4; ++i)
        cp16(Xs + (size_t)(row0 + sr + i * 32) * 1024 + sc * 8, &As[0][(tid + i * 256) * 8]);
    #pragma unroll
    for (int i = 0; i < 2; ++i)
        cp16(Wh + (size_t)(sr + i * 32) * 1024 + sc * 8, &Bs[0][(tid + i * 256) * 8]);
    asm volatile("s_waitcnt vmcnt(0)" ::: "memory");
    __syncthreads();

    int cur = 0;
    for (int kt = 0; kt < 16; ++kt) {
        if (kt < 15) {
            const int kb = (kt + 1) * 64;
            #pragma unroll
            for (int i = 0; i < 4; ++i)
                cp16(Xs + (size_t)(row0 + sr + i * 32) * 1024 + kb + sc * 8,
                     &As[cur ^ 1][(tid + i * 256) * 8]);
            #pragma unroll
            for (int i = 0; i < 2; ++i)
                cp16(Wh + (size_t)(sr + i * 32) * 1024 + kb + sc * 8,
                     &Bs[cur ^ 1][(tid + i * 256) * 8]);
        }
        bf16x8 af[2][2], bfr[4][2];
        #pragma unroll
        for (int c = 0; c < 2; ++c) {
            #pragma unroll
            for (int rb = 0; rb < 2; ++rb) {
                int row = wid * 32 + rb * 16 + lr;
                int chk = (c * 4 + lg) ^ (row & 7);
                af[rb][c] = *(const bf16x8*)&As[cur][row * 64 + chk * 8];
            }
            #pragma unroll
            for (int nb = 0; nb < 4; ++nb) {
                int brow = nb * 16 + lr;
                int chk = (c * 4 + lg) ^ (brow & 7);
                bfr[nb][c] = *(const bf16x8*)&Bs[cur][brow * 64 + chk * 8];
            }
        }
        #pragma unroll
        for (int c = 0; c < 2; ++c)
            #pragma unroll
            for (int nb = 0; nb < 4; ++nb)
                #pragma unroll
                for (int rb = 0; rb < 2; ++rb)
                    acc[rb][nb] = __builtin_amdgcn_mfma_f32_16x16x32_bf16(
                        af[rb][c], bfr[nb][c], acc[rb][nb], 0, 0, 0);
        asm volatile("s_waitcnt vmcnt(0)" ::: "memory");
        __syncthreads();
        cur ^= 1;
    }

    // epilogue: bf16 out, layout [b][h][s][d]
    #pragma unroll
    for (int rb = 0; rb < 2; ++rb)
        #pragma unroll
        for (int r = 0; r < 4; ++r) {
            int row = row0 + wid * 32 + rb * 16 + lg * 4 + r;
            int b = row >> 11, s = row & (S_ - 1);
            size_t base = (size_t)b * H_ * S_ * DH_ + (size_t)s * DH_;
            #pragma unroll
            for (int nb = 0; nb < 4; ++nb)
                Out[base + nb * 16 + lr] = f2bf(acc[rb][nb][r]);
        }
}

// ------------------------------------------------------- flash attention, MFMA
__global__ __launch_bounds__(256, 2)
void attn_kernel(const unsigned short* __restrict__ Q,
                 const unsigned short* __restrict__ K,
                 const unsigned short* __restrict__ V,
                 unsigned short* __restrict__ Cs)   // concat bf16, swizzled rows
{
    __shared__ unsigned short Vt[DH_][72];
    __shared__ unsigned short Plds[4][32][72];

    const int tid  = threadIdx.x;
    const int wid  = tid >> 6;
    const int lane = tid & 63;
    const int lg   = lane >> 4;
    const int lr   = lane & 15;
    const int bh   = blockIdx.y;
    const int b    = bh >> 4;
    const int h    = bh & 15;
    const int q0   = blockIdx.x * 128 + wid * 32;

    const unsigned short* Qbh = Q + (size_t)bh * S_ * DH_;
    const unsigned short* Kbh = K + (size_t)bh * S_ * DH_;
    const unsigned short* Vbh = V + (size_t)bh * S_ * DH_;

    bf16x8 qf[2][2];
    #pragma unroll
    for (int rb = 0; rb < 2; ++rb)
        #pragma unroll
        for (int c = 0; c < 2; ++c)
            qf[rb][c] = *(const bf16x8*)(Qbh + (size_t)(q0 + rb * 16 + lr) * DH_ + c * 32 + lg * 8);

    f32x4 oacc[2][4];
    float m_run[2][4], l_run[2][4];
    #pragma unroll
    for (int rb = 0; rb < 2; ++rb)
        #pragma unroll
        for (int r = 0; r < 4; ++r) { m_run[rb][r] = -1e30f; l_run[rb][r] = 0.f; }
    #pragma unroll
    for (int rb = 0; rb < 2; ++rb)
        #pragma unroll
        for (int nb = 0; nb < 4; ++nb) oacc[rb][nb] = (f32x4)(0.f);

    const int vkey = tid & 63;
    const int vd0  = (tid >> 6) * 16;

    for (int kt = 0; kt < S_ / 64; ++kt) {
        u16x8 v0 = *(const u16x8*)(Vbh + (size_t)(kt * 64 + vkey) * DH_ + vd0);
        u16x8 v1 = *(const u16x8*)(Vbh + (size_t)(kt * 64 + vkey) * DH_ + vd0 + 8);
        __syncthreads();
        #pragma unroll
        for (int i = 0; i < 8; ++i) {
            Vt[vd0 + i][vkey]     = v0[i];
            Vt[vd0 + 8 + i][vkey] = v1[i];
        }
        __syncthreads();

        f32x4 sf[2][4];
        #pragma unroll
        for (int rb = 0; rb < 2; ++rb)
            #pragma unroll
            for (int nb = 0; nb < 4; ++nb) sf[rb][nb] = (f32x4)(0.f);
        #pragma unroll
        for (int c = 0; c < 2; ++c) {
            #pragma unroll
            for (int nb = 0; nb < 4; ++nb) {
                bf16x8 kf = *(const bf16x8*)(Kbh + (size_t)(kt * 64 + nb * 16 + lr) * DH_ + c * 32 + lg * 8);
                #pragma unroll
                for (int rb = 0; rb < 2; ++rb)
                    sf[rb][nb] = __builtin_amdgcn_mfma_f32_16x16x32_bf16(qf[rb][c], kf, sf[rb][nb], 0, 0, 0);
            }
        }

        #pragma unroll
        for (int rb = 0; rb < 2; ++rb) {
            #pragma unroll
            for (int r = 0; r < 4; ++r) {
                float mloc = fmaxf(fmaxf(sf[rb][0][r], sf[rb][1][r]),
                                   fmaxf(sf[rb][2][r], sf[rb][3][r]));
                #pragma unroll
                for (int off = 1; off < 16; off <<= 1)
                    mloc = fmaxf(mloc, __shfl_xor(mloc, off));
                float mnew = fmaxf(m_run[rb][r], mloc);
                float a    = __expf(m_run[rb][r] - mnew);
                m_run[rb][r] = mnew;
                float rs = 0.f;
                #pragma unroll
                for (int nb = 0; nb < 4; ++nb) {
                    float p = __expf(sf[rb][nb][r] - mnew);
                    sf[rb][nb][r] = p;
                    rs += p;
                }
                #pragma unroll
                for (int off = 1; off < 16; off <<= 1)
                    rs += __shfl_xor(rs, off);
                l_run[rb][r] = l_run[rb][r] * a + rs;
                #pragma unroll
                for (int nb = 0; nb < 4; ++nb) oacc[rb][nb][r] *= a;
            }
        }

        #pragma unroll
        for (int rb = 0; rb < 2; ++rb)
            #pragma unroll
            for (int nb = 0; nb < 4; ++nb)
                #pragma unroll
                for (int r = 0; r < 4; ++r)
                    Plds[wid][rb * 16 + lg * 4 + r][nb * 16 + lr] = f2bf(sf[rb][nb][r]);
        __syncthreads();

        #pragma unroll
        for (int c = 0; c < 2; ++c) {
            bf16x8 pa[2];
            #pragma unroll
            for (int rb = 0; rb < 2; ++rb)
                pa[rb] = *(const bf16x8*)&Plds[wid][rb * 16 + lr][c * 32 + lg * 8];
            #pragma unroll
            for (int nb = 0; nb < 4; ++nb) {
                bf16x8 vf = *(const bf16x8*)&Vt[nb * 16 + lr][c * 32 + lg * 8];
                #pragma unroll
                for (int rb = 0; rb < 2; ++rb)
                    oacc[rb][nb] = __builtin_amdgcn_mfma_f32_16x16x32_bf16(pa[rb], vf, oacc[rb][nb], 0, 0, 0);
            }
        }
    }

    // epilogue: bf16 concat [8192][1024], rows chunk-swizzled for oproj staging
    #pragma unroll
    for (int rb = 0; rb < 2; ++rb) {
        #pragma unroll
        for (int r = 0; r < 4; ++r) {
            int srow = q0 + rb * 16 + lg * 4 + r;
            size_t grow = (size_t)b * S_ + srow;
            float inv = 1.f / l_run[rb][r];
            #pragma unroll
            for (int nb = 0; nb < 4; ++nb) {
                int cc  = nb * 16 + lr;
                int chk = (cc >> 3) ^ (srow & 7);
                Cs[grow * 1024 + h * 64 + chk * 8 + (cc & 7)] = f2bf(oacc[rb][nb][r] * inv);
            }
        }
    }
}

// ---------------------------------------------------------- output proj MFMA
__global__ __launch_bounds__(256, 2)
void oproj_mfma(const unsigned short* __restrict__ Cs,
                const unsigned short* __restrict__ Wot,
                const float* __restrict__ bo,
                float* __restrict__ out)
{
    __shared__ __align__(16) unsigned short As[2][128 * 64];
    __shared__ __align__(16) unsigned short Bs[2][64 * 64];

    const int tid  = threadIdx.x;
    const int wid  = tid >> 6;
    const int lane = tid & 63;
    const int lg   = lane >> 4;
    const int lr   = lane & 15;
    const int row0 = blockIdx.x * 128;
    const int col0 = blockIdx.y * 64;

    const int sr = tid >> 3;
    const int sc = tid & 7;

    f32x4 acc[2][4];
    #pragma unroll
    for (int rb = 0; rb < 2; ++rb)
        #pragma unroll
        for (int nb = 0; nb < 4; ++nb) acc[rb][nb] = (f32x4)(0.f);

    #pragma unroll
    for (int i = 0; i < 4; ++i)
        cp16(Cs + (size_t)(row0 + sr + i * 32) * 1024 + sc * 8, &As[0][(tid + i * 256) * 8]);
    #pragma unroll
    for (int i = 0; i < 2; ++i)
        cp16(Wot + (size_t)(col0 + sr + i * 32) * 1024 + sc * 8, &Bs[0][(tid + i * 256) * 8]);
    asm volatile("s_waitcnt vmcnt(0)" ::: "memory");
    __syncthreads();

    int cur = 0;
    for (int kt = 0; kt < 16; ++kt) {
        if (kt < 15) {
            const int kb = (kt + 1) * 64;
            #pragma unroll
            for (int i = 0; i < 4; ++i)
                cp16(Cs + (size_t)(row0 + sr + i * 32) * 1024 + kb + sc * 8,
                     &As[cur ^ 1][(tid + i * 256) * 8]);
            #pragma unroll
            for (int i = 0; i < 2; ++i)
                cp16(Wot + (size_t)(col0 + sr + i * 32) * 1024 + kb + sc * 8,
                     &Bs[cur ^ 1][(tid + i * 256) * 8]);
        }
        bf16x8 af[2][2], bfr[4][2];
        #pragma unroll
        for (int c = 0; c < 2; ++c) {
            #pragma unroll
            for (int rb = 0; rb < 2; ++rb) {
                int row = wid * 32 + rb * 16 + lr;
                int chk = (c * 4 + lg) ^ (row & 7);
                af[rb][c] = *(const bf16x8*)&As[cur][row * 64 + chk * 8];
            }
            #pragma unroll
            for (int nb = 0; nb < 4; ++nb) {
                int brow = nb * 16 + lr;
                int chk = (c * 4 + lg) ^ (brow & 7);
                bfr[nb][c] = *(const bf16x8*)&Bs[cur][brow * 64 + chk * 8];
            }
        }
        #pragma unroll
        for (int c = 0; c < 2; ++c)
            #pragma unroll
            for (int nb = 0; nb < 4; ++nb)
                #pragma unroll
                for (int rb = 0; rb < 2; ++rb)
                    acc[rb][nb] = __builtin_amdgcn_mfma_f32_16x16x32_bf16(
                        af[rb][c], bfr[nb][c], acc[rb][nb], 0, 0, 0);
        asm volatile("s_waitcnt vmcnt(0)" ::: "memory");
        __syncthreads();
        cur ^= 1;
    }

    float bb[4];
    #pragma unroll
    for (int nb = 0; nb < 4; ++nb) bb[nb] = bo[col0 + nb * 16 + lr];
    #pragma unroll
    for (int rb = 0; rb < 2; ++rb)
        #pragma unroll
        for (int r = 0; r < 4; ++r) {
            int row = row0 + wid * 32 + rb * 16 + lg * 4 + r;
            #pragma unroll
            for (int nb = 0; nb < 4; ++nb)
                out[(size_t)row * 1024 + col0 + nb * 16 + lr] = acc[rb][nb][r] + bb[nb];
        }
}

extern "C" void kernel_launch(void* const* d_in, const int* in_sizes, int n_in,
                              void* d_out, int out_size, void* d_ws, size_t ws_size,
                              hipStream_t stream) {
    const float* x  = (const float*)d_in[0];
    const float* Wq = (const float*)d_in[1];
    const float* Wk = (const float*)d_in[2];
    const float* Wv = (const float*)d_in[3];
    const float* Wo = (const float*)d_in[4];
    const float* bo = (const float*)d_in[5];
    float* out = (float*)d_out;

    const size_t perQ = (size_t)B_ * H_ * S_ * DH_;        // 8.39M elems
    unsigned short* xs  = (unsigned short*)d_ws;           // 16.8MB
    unsigned short* Wt  = xs + (size_t)8192 * 1024;        // 6.3MB
    unsigned short* Wot = Wt + (size_t)48 * 64 * 1024;     // 2.1MB
    unsigned short* Qb  = Wot + (size_t)1024 * 1024;
    unsigned short* Kb  = Qb + perQ;
    unsigned short* Vb  = Kb + perQ;
    unsigned short* Cb  = Vb + perQ;                       // concat bf16 swz

    conv_x<<<4096, 256, 0, stream>>>(x, xs);
    conv_wqkv<<<dim3(16, 48), 256, 0, stream>>>(Wq, Wk, Wv, Wt);
    conv_wo<<<dim3(16, 16), 256, 0, stream>>>(Wo, Wot);
    qkv_mfma<<<dim3(64, 48), 256, 0, stream>>>(xs, Wt, Qb, Kb, Vb);
    attn_kernel<<<dim3(16, 64), 256, 0, stream>>>(Qb, Kb, Vb, Cb);
    oproj_mfma<<<dim3(64, 16), 256, 0, stream>>>(Cb, Wot, bo, out);
}

// Round 4
// 363.296 us; speedup vs baseline: 5.5903x; 1.1357x over previous
//
#include <hip/hip_runtime.h>

#define B_  4
#define S_  2048
#define D_  1024
#define H_  16
#define DH_ 64

typedef __attribute__((ext_vector_type(8)))  short bf16x8;
typedef __attribute__((ext_vector_type(4)))  float f32x4;
typedef __attribute__((ext_vector_type(16))) float f32x16;
typedef __attribute__((ext_vector_type(8)))  unsigned short u16x8;
typedef __attribute__((ext_vector_type(4)))  unsigned int u32x4;

__device__ __forceinline__ unsigned short f2bf(float x) {
    unsigned int u = __builtin_bit_cast(unsigned int, x);
    u += 0x7fffu + ((u >> 16) & 1u);            // round-to-nearest-even
    return (unsigned short)(u >> 16);
}

__device__ __forceinline__ float fexp2(float x) {
#if __has_builtin(__builtin_amdgcn_exp2f)
    return __builtin_amdgcn_exp2f(x);
#else
    return exp2f(x);
#endif
}

__device__ __forceinline__ unsigned int cvtpk(float lo, float hi) {
    unsigned int r;
    asm("v_cvt_pk_bf16_f32 %0, %1, %2" : "=v"(r) : "v"(lo), "v"(hi));
    return r;
}

// async global->LDS, 16B per lane
__device__ __forceinline__ void cp16(const void* g, void* l) {
    typedef const __attribute__((address_space(1))) unsigned int* gp_t;
    typedef __attribute__((address_space(3))) unsigned int* lp_t;
    __builtin_amdgcn_global_load_lds((gp_t)(unsigned long long)(size_t)g,
                                     (lp_t)(unsigned int)(size_t)l, 16, 0, 0);
}

// ---------------------------------------------------------------- converts
__global__ __launch_bounds__(256)
void conv_x(const float* __restrict__ x, unsigned short* __restrict__ xs)
{
    int gid = blockIdx.x * 256 + threadIdx.x;
    int row = gid >> 7;
    int rem = gid & 127;
    int blk = rem >> 3;
    int c   = rem & 7;
    const float* src = x + (size_t)row * 1024 + blk * 64 + c * 8;
    float4 a = *(const float4*)src;
    float4 b = *(const float4*)(src + 4);
    u16x8 v;
    v[0] = f2bf(a.x); v[1] = f2bf(a.y); v[2] = f2bf(a.z); v[3] = f2bf(a.w);
    v[4] = f2bf(b.x); v[5] = f2bf(b.y); v[6] = f2bf(b.z); v[7] = f2bf(b.w);
    *(u16x8*)(xs + (size_t)row * 1024 + blk * 64 + ((c ^ (row & 7)) * 8)) = v;
}

// Q's weights pre-scaled by (1/sqrt(DH)) * log2(e) -> attn works in exp2 domain.
__global__ __launch_bounds__(256)
void conv_wqkv(const float* __restrict__ Wq, const float* __restrict__ Wk,
               const float* __restrict__ Wv, unsigned short* __restrict__ Wt)
{
    __shared__ float Wl[64][65];
    const int tid = threadIdx.x;
    const int kt  = blockIdx.x;
    const int y   = blockIdx.y;
    const int mat = y >> 4, h = y & 15;
    const float* W = (mat == 0 ? Wq : (mat == 1 ? Wk : Wv)) + (size_t)h * 1024 * 64;
    const float sc = (mat == 0) ? 0.125f * 1.4426950408889634f : 1.0f;
    #pragma unroll
    for (int i = 0; i < 4; ++i) {
        int idx = tid + i * 256;
        int kk = idx >> 4, c4 = (idx & 15) * 4;
        *(float4*)&Wl[kk][c4] = *(const float4*)&W[(size_t)(kt * 64 + kk) * 64 + c4];
    }
    __syncthreads();
    #pragma unroll
    for (int i = 0; i < 2; ++i) {
        int cid = tid + i * 256;
        int c = cid >> 3, kc = cid & 7;
        u16x8 v;
        #pragma unroll
        for (int j = 0; j < 8; ++j) v[j] = f2bf(Wl[kc * 8 + j][c] * sc);
        *(u16x8*)(Wt + ((size_t)y * 64 + c) * 1024 + kt * 64 + ((kc ^ (c & 7)) * 8)) = v;
    }
}

__global__ __launch_bounds__(256)
void conv_wo(const float* __restrict__ Wo, unsigned short* __restrict__ Wot)
{
    __shared__ float Wl[64][65];
    const int tid = threadIdx.x;
    const int kt = blockIdx.x, ct = blockIdx.y;
    #pragma unroll
    for (int i = 0; i < 4; ++i) {
        int idx = tid + i * 256;
        int kk = idx >> 4, c4 = (idx & 15) * 4;
        *(float4*)&Wl[kk][c4] = *(const float4*)&Wo[(size_t)(kt * 64 + kk) * 1024 + ct * 64 + c4];
    }
    __syncthreads();
    #pragma unroll
    for (int i = 0; i < 2; ++i) {
        int cid = tid + i * 256;
        int c = cid >> 3, kc = cid & 7;
        u16x8 v;
        #pragma unroll
        for (int j = 0; j < 8; ++j) v[j] = f2bf(Wl[kc * 8 + j][c]);
        *(u16x8*)(Wot + (size_t)(ct * 64 + c) * 1024 + kt * 64 + ((kc ^ (c & 7)) * 8)) = v;
    }
}

// ------------------------------------------------------------ QKV MFMA GEMM
__global__ __launch_bounds__(256, 2)
void qkv_mfma(const unsigned short* __restrict__ Xs,
              const unsigned short* __restrict__ Wt,
              unsigned short* __restrict__ Qo,
              unsigned short* __restrict__ Ko,
              unsigned short* __restrict__ Vo)
{
    __shared__ __align__(16) unsigned short As[2][128 * 64];
    __shared__ __align__(16) unsigned short Bs[2][64 * 64];

    const int tid  = threadIdx.x;
    const int wid  = tid >> 6;
    const int lane = tid & 63;
    const int lg   = lane >> 4;
    const int lr   = lane & 15;
    const int row0 = blockIdx.x * 128;
    const int y    = blockIdx.y;
    const int mat  = y >> 4;
    const int h    = y & 15;

    const unsigned short* Wh = Wt + (size_t)y * (64 * 1024);
    unsigned short* Out = (mat == 0 ? Qo : (mat == 1 ? Ko : Vo)) + (size_t)h * S_ * DH_;

    const int sr = tid >> 3;
    const int sc = tid & 7;

    f32x4 acc[2][4];
    #pragma unroll
    for (int rb = 0; rb < 2; ++rb)
        #pragma unroll
        for (int nb = 0; nb < 4; ++nb) acc[rb][nb] = (f32x4)(0.f);

    #pragma unroll
    for (int i = 0; i < 4; ++i)
        cp16(Xs + (size_t)(row0 + sr + i * 32) * 1024 + sc * 8, &As[0][(tid + i * 256) * 8]);
    #pragma unroll
    for (int i = 0; i < 2; ++i)
        cp16(Wh + (size_t)(sr + i * 32) * 1024 + sc * 8, &Bs[0][(tid + i * 256) * 8]);
    asm volatile("s_waitcnt vmcnt(0)" ::: "memory");
    __syncthreads();

    int cur = 0;
    for (int kt = 0; kt < 16; ++kt) {
        if (kt < 15) {
            const int kb = (kt + 1) * 64;
            #pragma unroll
            for (int i = 0; i < 4; ++i)
                cp16(Xs + (size_t)(row0 + sr + i * 32) * 1024 + kb + sc * 8,
                     &As[cur ^ 1][(tid + i * 256) * 8]);
            #pragma unroll
            for (int i = 0; i < 2; ++i)
                cp16(Wh + (size_t)(sr + i * 32) * 1024 + kb + sc * 8,
                     &Bs[cur ^ 1][(tid + i * 256) * 8]);
        }
        bf16x8 af[2][2], bfr[4][2];
        #pragma unroll
        for (int c = 0; c < 2; ++c) {
            #pragma unroll
            for (int rb = 0; rb < 2; ++rb) {
                int row = wid * 32 + rb * 16 + lr;
                int chk = (c * 4 + lg) ^ (row & 7);
                af[rb][c] = *(const bf16x8*)&As[cur][row * 64 + chk * 8];
            }
            #pragma unroll
            for (int nb = 0; nb < 4; ++nb) {
                int brow = nb * 16 + lr;
                int chk = (c * 4 + lg) ^ (brow & 7);
                bfr[nb][c] = *(const bf16x8*)&Bs[cur][brow * 64 + chk * 8];
            }
        }
        #pragma unroll
        for (int c = 0; c < 2; ++c)
            #pragma unroll
            for (int nb = 0; nb < 4; ++nb)
                #pragma unroll
                for (int rb = 0; rb < 2; ++rb)
                    acc[rb][nb] = __builtin_amdgcn_mfma_f32_16x16x32_bf16(
                        af[rb][c], bfr[nb][c], acc[rb][nb], 0, 0, 0);
        asm volatile("s_waitcnt vmcnt(0)" ::: "memory");
        __syncthreads();
        cur ^= 1;
    }

    #pragma unroll
    for (int rb = 0; rb < 2; ++rb)
        #pragma unroll
        for (int r = 0; r < 4; ++r) {
            int row = row0 + wid * 32 + rb * 16 + lg * 4 + r;
            int b = row >> 11, s = row & (S_ - 1);
            size_t base = (size_t)b * H_ * S_ * DH_ + (size_t)s * DH_;
            #pragma unroll
            for (int nb = 0; nb < 4; ++nb)
                Out[base + nb * 16 + lr] = f2bf(acc[rb][nb][r]);
        }
}

// --------------------------------------------- flash attention, 32x32 swapped
// 4 waves/block, each wave owns 32 q-rows (lane owns q = lane&31). KV tile 64.
// S^T = mfma(K,Q): lane q-local softmax. P packed in-reg (cvt_pk + shfl32).
// O^T = mfma(V^T, P): per-lane scalar m/l/rescale. V^T staged in swizzled LDS.
__global__ __launch_bounds__(256, 2)
void attn_kernel(const unsigned short* __restrict__ Q,
                 const unsigned short* __restrict__ K,
                 const unsigned short* __restrict__ V,
                 unsigned short* __restrict__ Cs)
{
    __shared__ __align__(16) unsigned short Vt[64 * 64];     // [d][key], chunk-XOR swz
    __shared__ __align__(16) unsigned short Olds[4][32 * 72];

    const int tid  = threadIdx.x;
    const int wid  = tid >> 6;
    const int lane = tid & 63;
    const int h    = lane >> 5;     // lane half
    const int q31  = lane & 31;     // this lane's q-row (and A-frag row)
    const int bh   = blockIdx.y;
    const int b    = bh >> 4;
    const int hh   = bh & 15;
    const int q0   = blockIdx.x * 128;
    const int qrow = q0 + wid * 32 + q31;

    const unsigned short* Qbh = Q + (size_t)bh * S_ * DH_;
    const unsigned short* Kbh = K + (size_t)bh * S_ * DH_;
    const unsigned short* Vbh = V + (size_t)bh * S_ * DH_;

    // Q fragments (B operand; rows = q): lane -> row q31, d = dc*16 + h*8
    bf16x8 qf[4];
    #pragma unroll
    for (int dc = 0; dc < 4; ++dc)
        qf[dc] = *(const bf16x8*)(Qbh + (size_t)qrow * DH_ + dc * 16 + h * 8);

    f32x16 oacc[2];
    oacc[0] = (f32x16)0.f;
    oacc[1] = (f32x16)0.f;
    float m = -1e30f, lsum = 0.f;

    const int vk = (tid & 15) * 4;   // staging: 4 keys
    const int vd = (tid >> 4) * 4;   // staging: 4 d-cols

    for (int kt = 0; kt < S_ / 64; ++kt) {
        // ---- stage V transposed: 4 global 8B loads + 4 LDS b64 writes ----
        ushort va[4][4];
        #pragma unroll
        for (int i = 0; i < 4; ++i) {
            ushort4 t = *(const ushort4*)(Vbh + (size_t)(kt * 64 + vk + i) * DH_ + vd);
            va[i][0] = t.x; va[i][1] = t.y; va[i][2] = t.z; va[i][3] = t.w;
        }
        __syncthreads();             // prior tile's Vt reads complete
        #pragma unroll
        for (int j = 0; j < 4; ++j) {
            int d = vd + j;
            ushort4 w = make_ushort4(va[0][j], va[1][j], va[2][j], va[3][j]);
            *(ushort4*)&Vt[d * 64 + (((vk >> 3) ^ (d & 7)) << 3) + (vk & 7)] = w;
        }
        __syncthreads();             // Vt visible

        // ---- S^T = K Q^T: D rows = key, cols = q (lane&31) ----
        f32x16 sf[2];
        #pragma unroll
        for (int kb = 0; kb < 2; ++kb) {
            bf16x8 kf[4];
            #pragma unroll
            for (int dc = 0; dc < 4; ++dc)
                kf[dc] = *(const bf16x8*)(Kbh + (size_t)(kt * 64 + kb * 32 + q31) * DH_ + dc * 16 + h * 8);
            f32x16 s = (f32x16)0.f;
            #pragma unroll
            for (int dc = 0; dc < 4; ++dc)
                s = __builtin_amdgcn_mfma_f32_32x32x16_bf16(kf[dc], qf[dc], s, 0, 0, 0);
            sf[kb] = s;
        }

        // ---- lane-local online softmax (exp2 domain; defer-max THR=8) ----
        float mx = -1e30f;
        #pragma unroll
        for (int kb = 0; kb < 2; ++kb)
            #pragma unroll
            for (int r = 0; r < 16; r += 4)
                mx = fmaxf(mx, fmaxf(fmaxf(sf[kb][r], sf[kb][r + 1]),
                                     fmaxf(sf[kb][r + 2], sf[kb][r + 3])));
        mx = fmaxf(mx, __shfl_xor(mx, 32));
        if (!__all(mx <= m + 8.f)) {
            float mnew = fmaxf(m, mx);
            float a = fexp2(m - mnew);
            m = mnew;
            lsum *= a;
            oacc[0] *= a;
            oacc[1] *= a;
        }
        float p0 = 0.f, p1 = 0.f, p2 = 0.f, p3 = 0.f;
        #pragma unroll
        for (int kb = 0; kb < 2; ++kb)
            #pragma unroll
            for (int r = 0; r < 16; r += 4) {
                float e0 = fexp2(sf[kb][r]     - m);
                float e1 = fexp2(sf[kb][r + 1] - m);
                float e2 = fexp2(sf[kb][r + 2] - m);
                float e3 = fexp2(sf[kb][r + 3] - m);
                sf[kb][r] = e0; sf[kb][r + 1] = e1; sf[kb][r + 2] = e2; sf[kb][r + 3] = e3;
                p0 += e0; p1 += e1; p2 += e2; p3 += e3;
            }
        float ps = (p0 + p1) + (p2 + p3);
        ps += __shfl_xor(ps, 32);
        lsum += ps;

        // ---- pack P to bf16 pairs; exchange halves; feed PV directly ----
        // own[kb][j] covers keys kb*32 + 8*(j>>1) + 4*h + 2*(j&1) + {0,1}
        unsigned int own[2][8], swp[2][8];
        #pragma unroll
        for (int kb = 0; kb < 2; ++kb)
            #pragma unroll
            for (int j = 0; j < 8; ++j)
                own[kb][j] = cvtpk(sf[kb][2 * j], sf[kb][2 * j + 1]);
        #pragma unroll
        for (int kb = 0; kb < 2; ++kb)
            #pragma unroll
            for (int j = 0; j < 8; ++j)
                swp[kb][j] = (unsigned int)__shfl_xor((int)own[kb][j], 32);

        // ---- O^T += V^T P^T: D rows = d, cols = q ----
        #pragma unroll
        for (int kB = 0; kB < 4; ++kB) {
            const int kb = kB >> 1;
            const int J  = (kB & 1) * 4;
            unsigned int b0 = h ? swp[kb][J + 2] : own[kb][J + 0];
            unsigned int b1 = h ? swp[kb][J + 3] : own[kb][J + 1];
            unsigned int b2 = h ? own[kb][J + 2] : swp[kb][J + 0];
            unsigned int b3 = h ? own[kb][J + 3] : swp[kb][J + 1];
            u32x4 pw = {b0, b1, b2, b3};
            bf16x8 pb = __builtin_bit_cast(bf16x8, pw);
            #pragma unroll
            for (int dh = 0; dh < 2; ++dh) {
                int drow = dh * 32 + q31;
                bf16x8 vf = *(const bf16x8*)&Vt[drow * 64 + (((kB * 2 + h) ^ (q31 & 7)) << 3)];
                oacc[dh] = __builtin_amdgcn_mfma_f32_32x32x16_bf16(vf, pb, oacc[dh], 0, 0, 0);
            }
        }
    }

    // ---- epilogue: normalize, transpose via per-wave LDS, swizzled stores ----
    float inv = 1.f / lsum;
    #pragma unroll
    for (int dh = 0; dh < 2; ++dh)
        #pragma unroll
        for (int r = 0; r < 16; ++r) {
            int d = dh * 32 + (r & 3) + ((r >> 2) << 3) + h * 4;
            Olds[wid][q31 * 72 + d] = f2bf(oacc[dh][r] * inv);
        }
    __syncthreads();
    const int orow = lane >> 1;
    const int srow = q0 + wid * 32 + orow;
    unsigned short* gout = Cs + ((size_t)b * S_ + srow) * 1024 + hh * 64;
    #pragma unroll
    for (int c = 0; c < 4; ++c) {
        int ch  = (lane & 1) * 4 + c;
        int chs = ch ^ (srow & 7);
        u16x8 v = *(const u16x8*)&Olds[wid][orow * 72 + ch * 8];
        *(u16x8*)(gout + chs * 8) = v;
    }
}

// ---------------------------------------------------------- output proj MFMA
__global__ __launch_bounds__(256, 2)
void oproj_mfma(const unsigned short* __restrict__ Cs,
                const unsigned short* __restrict__ Wot,
                const float* __restrict__ bo,
                float* __restrict__ out)
{
    __shared__ __align__(16) unsigned short As[2][128 * 64];
    __shared__ __align__(16) unsigned short Bs[2][64 * 64];

    const int tid  = threadIdx.x;
    const int wid  = tid >> 6;
    const int lane = tid & 63;
    const int lg   = lane >> 4;
    const int lr   = lane & 15;
    const int row0 = blockIdx.x * 128;
    const int col0 = blockIdx.y * 64;

    const int sr = tid >> 3;
    const int sc = tid & 7;

    f32x4 acc[2][4];
    #pragma unroll
    for (int rb = 0; rb < 2; ++rb)
        #pragma unroll
        for (int nb = 0; nb < 4; ++nb) acc[rb][nb] = (f32x4)(0.f);

    #pragma unroll
    for (int i = 0; i < 4; ++i)
        cp16(Cs + (size_t)(row0 + sr + i * 32) * 1024 + sc * 8, &As[0][(tid + i * 256) * 8]);
    #pragma unroll
    for (int i = 0; i < 2; ++i)
        cp16(Wot + (size_t)(col0 + sr + i * 32) * 1024 + sc * 8, &Bs[0][(tid + i * 256) * 8]);
    asm volatile("s_waitcnt vmcnt(0)" ::: "memory");
    __syncthreads();

    int cur = 0;
    for (int kt = 0; kt < 16; ++kt) {
        if (kt < 15) {
            const int kb = (kt + 1) * 64;
            #pragma unroll
            for (int i = 0; i < 4; ++i)
                cp16(Cs + (size_t)(row0 + sr + i * 32) * 1024 + kb + sc * 8,
                     &As[cur ^ 1][(tid + i * 256) * 8]);
            #pragma unroll
            for (int i = 0; i < 2; ++i)
                cp16(Wot + (size_t)(col0 + sr + i * 32) * 1024 + kb + sc * 8,
                     &Bs[cur ^ 1][(tid + i * 256) * 8]);
        }
        bf16x8 af[2][2], bfr[4][2];
        #pragma unroll
        for (int c = 0; c < 2; ++c) {
            #pragma unroll
            for (int rb = 0; rb < 2; ++rb) {
                int row = wid * 32 + rb * 16 + lr;
                int chk = (c * 4 + lg) ^ (row & 7);
                af[rb][c] = *(const bf16x8*)&As[cur][row * 64 + chk * 8];
            }
            #pragma unroll
            for (int nb = 0; nb < 4; ++nb) {
                int brow = nb * 16 + lr;
                int chk = (c * 4 + lg) ^ (brow & 7);
                bfr[nb][c] = *(const bf16x8*)&Bs[cur][brow * 64 + chk * 8];
            }
        }
        #pragma unroll
        for (int c = 0; c < 2; ++c)
            #pragma unroll
            for (int nb = 0; nb < 4; ++nb)
                #pragma unroll
                for (int rb = 0; rb < 2; ++rb)
                    acc[rb][nb] = __builtin_amdgcn_mfma_f32_16x16x32_bf16(
                        af[rb][c], bfr[nb][c], acc[rb][nb], 0, 0, 0);
        asm volatile("s_waitcnt vmcnt(0)" ::: "memory");
        __syncthreads();
        cur ^= 1;
    }

    float bb[4];
    #pragma unroll
    for (int nb = 0; nb < 4; ++nb) bb[nb] = bo[col0 + nb * 16 + lr];
    #pragma unroll
    for (int rb = 0; rb < 2; ++rb)
        #pragma unroll
        for (int r = 0; r < 4; ++r) {
            int row = row0 + wid * 32 + rb * 16 + lg * 4 + r;
            #pragma unroll
            for (int nb = 0; nb < 4; ++nb)
                out[(size_t)row * 1024 + col0 + nb * 16 + lr] = acc[rb][nb][r] + bb[nb];
        }
}

extern "C" void kernel_launch(void* const* d_in, const int* in_sizes, int n_in,
                              void* d_out, int out_size, void* d_ws, size_t ws_size,
                              hipStream_t stream) {
    const float* x  = (const float*)d_in[0];
    const float* Wq = (const float*)d_in[1];
    const float* Wk = (const float*)d_in[2];
    const float* Wv = (const float*)d_in[3];
    const float* Wo = (const float*)d_in[4];
    const float* bo = (const float*)d_in[5];
    float* out = (float*)d_out;

    const size_t perQ = (size_t)B_ * H_ * S_ * DH_;
    unsigned short* xs  = (unsigned short*)d_ws;
    unsigned short* Wt  = xs + (size_t)8192 * 1024;
    unsigned short* Wot = Wt + (size_t)48 * 64 * 1024;
    unsigned short* Qb  = Wot + (size_t)1024 * 1024;
    unsigned short* Kb  = Qb + perQ;
    unsigned short* Vb  = Kb + perQ;
    unsigned short* Cb  = Vb + perQ;

    conv_x<<<4096, 256, 0, stream>>>(x, xs);
    conv_wqkv<<<dim3(16, 48), 256, 0, stream>>>(Wq, Wk, Wv, Wt);
    conv_wo<<<dim3(16, 16), 256, 0, stream>>>(Wo, Wot);
    qkv_mfma<<<dim3(64, 48), 256, 0, stream>>>(xs, Wt, Qb, Kb, Vb);
    attn_kernel<<<dim3(16, 64), 256, 0, stream>>>(Qb, Kb, Vb, Cb);
    oproj_mfma<<<dim3(64, 16), 256, 0, stream>>>(Cb, Wot, bo, out);
}